// Round 1
// baseline (597.915 us; speedup 1.0000x reference)
//
#include <hip/hip_runtime.h>

// FlowNet correlation, max_disp=4 -> 81 displacement channels, mean over C, LeakyReLU(0.1).
// B=8 C=128 H=128 W=256 fp32 NCHW.
//
// Block = 576 threads = 9 waves; wave wv handles displacement row dy=wv.
// Lane owns 8 consecutive pixels of an 8x64 spatial tile -> acc[9 dx][8 px] in regs.
// x2 halo tile (16 x 72, stride 76) double-buffered in LDS, 4 channels/chunk.
//
// R3 (this version) — latency-bound fix (VALUBusy was 22.8%, all pipes idle):
//  1. Issue order per chunk: [x1 a4 loads][x2 sreg prefetch][LDS-ping-pong compute][commit].
//     vmcnt retires in issue order, so x1 MUST precede the x2 HBM prefetch or every
//     per-channel x1 wait silently drains ~900cy of HBM latency (the R2 serializer).
//     sched_barrier(0) pins the issue blocks.
//  2. xr[2][16] ping-pong: next channel's 4 ds_read_b128 issue under current 144cy of FMA.
//  3. Lane remap r=l&7, cb=(l>>3)<<3: each 8-lane LDS service phase (128B/cy) now spans
//     8 rows (stride 76 = 12 banks) -> 8 distinct 4-bank groups -> conflict-free.
//     Old r=l>>3 put a phase in one row -> 2-way conflict (4.3 extra cyc per b128).
//     Address SETs for x1 loads / C stores are unchanged by the remap.
//  4. x2 staging as float4 (288 threads per channel-pair) -> half the staging instrs.
// VGPR budget: acc 72 + a4 32 + xr 32 + sreg 8 + addr ~= 160; must stay <=168 for the
// 9-wave block (3 waves/SIMD). Watch WRITE_SIZE for scratch spill evidence.

constexpr int MAXD = 4;
constexpr int ND   = 9;            // displacements per axis
constexpr int NDISP = 81;
constexpr int Bb = 8, Cc = 128, Hh = 128, Ww = 256;
constexpr int TH = 8, TW = 64, NPIX = 8;
constexpr int CK = 4;              // channels per staged chunk
constexpr int NCHUNK = Cc / CK;    // 32
constexpr int XROWS = TH + 2 * MAXD;   // 16
constexpr int XSTR  = 76;              // padded row stride (72 used)
constexpr int CH_TILE = XROWS * XSTR;  // 1216 floats / channel
constexpr int BUFF = CK * CH_TILE;     // 4864 floats / buffer
constexpr int NTHREADS = ND * 64;      // 576
constexpr int HW = Hh * Ww;            // 32768
constexpr float SCALE = 1.0f / 128.0f;
constexpr float SLOPE = 0.1f;

__global__ __launch_bounds__(NTHREADS, 1)
void corr81_kernel(const float* __restrict__ x1, const float* __restrict__ x2,
                   float* __restrict__ out) {
  const int tid = threadIdx.x;
  const int wv  = tid >> 6;          // dy = wv, 0..8
  const int l   = tid & 63;
  const int r   = l & 7;             // pixel row in tile (remapped, see R3.3)
  const int cb  = (l >> 3) << 3;     // pixel col base, 0..56

  const int w0 = blockIdx.x * TW;
  const int h0 = blockIdx.y * TH;
  const int b  = blockIdx.z;

  __shared__ __align__(16) float x2s[2 * BUFF];    // 38912 B

  // --- staging coords: 576 threads = 2 channel-pairs x 288 threads; one float4 each.
  const int cp   = tid / 288;                // channel pair: covers channels 2cp, 2cp+1
  const int st   = tid - cp * 288;           // 0..287
  const int srow = st / 18;                  // 0..15
  const int scol = (st - srow * 18) * 4;     // 0..68, multiple of 4
  const int gh2  = h0 - MAXD + srow;
  const int gw2  = w0 - MAXD + scol;
  const bool sok = (gh2 >= 0) && (gh2 < Hh) && (gw2 >= 0) && (gw2 + 3 < Ww + 1);
  const int x2base = b * (Cc * HW) + gh2 * Ww + gw2;   // valid only when sok
  const int sldso  = srow * XSTR + scol;
  const int chp0   = cp * 2;

  // --- compute-side addresses
  const int x1base = (b * Cc * Hh + h0 + r) * Ww + w0 + cb;
  const int ldro   = (r + wv) * XSTR + cb;   // LDS row (r+dy), col cb (reads cb..cb+15)

  float acc[ND][NPIX];
#pragma unroll
  for (int dx = 0; dx < ND; ++dx)
#pragma unroll
    for (int i = 0; i < NPIX; ++i) acc[dx][i] = 0.0f;

  auto ldx2 = [](const float* lp, float* dst) {
    float4 q0 = *reinterpret_cast<const float4*>(lp);
    float4 q1 = *reinterpret_cast<const float4*>(lp + 4);
    float4 q2 = *reinterpret_cast<const float4*>(lp + 8);
    float4 q3 = *reinterpret_cast<const float4*>(lp + 12);
    dst[0]  = q0.x; dst[1]  = q0.y; dst[2]  = q0.z; dst[3]  = q0.w;
    dst[4]  = q1.x; dst[5]  = q1.y; dst[6]  = q1.z; dst[7]  = q1.w;
    dst[8]  = q2.x; dst[9]  = q2.y; dst[10] = q2.z; dst[11] = q2.w;
    dst[12] = q3.x; dst[13] = q3.y; dst[14] = q3.z; dst[15] = q3.w;
  };

  // --- prologue: stage chunk 0
#pragma unroll
  for (int j = 0; j < 2; ++j) {
    float4 v = make_float4(0.0f, 0.0f, 0.0f, 0.0f);
    if (sok) v = *reinterpret_cast<const float4*>(x2 + x2base + (chp0 + j) * HW);
    *reinterpret_cast<float4*>(&x2s[(chp0 + j) * CH_TILE + sldso]) = v;
  }
  __syncthreads();

#pragma unroll 1
  for (int k = 0; k < NCHUNK; ++k) {
    const int kn = k + 1;

    // 1) x1 loads for this chunk's 4 channels — FIRST in vmem issue order, so their
    //    consumption never waits on the x2 HBM prefetch behind them in the queue.
    float a4[CK][NPIX];
#pragma unroll
    for (int c = 0; c < CK; ++c) {
      const float* p = x1 + x1base + (k * CK + c) * HW;
      float4 t0 = *reinterpret_cast<const float4*>(p);
      float4 t1 = *reinterpret_cast<const float4*>(p + 4);
      a4[c][0] = t0.x; a4[c][1] = t0.y; a4[c][2] = t0.z; a4[c][3] = t0.w;
      a4[c][4] = t1.x; a4[c][5] = t1.y; a4[c][6] = t1.z; a4[c][7] = t1.w;
    }
    __builtin_amdgcn_sched_barrier(0);

    // 2) x2 prefetch for next chunk; ~900cy HBM latency covered by this chunk's compute,
    //    drained only at the commit below.
    float4 sreg[2];
    if (kn < NCHUNK) {
#pragma unroll
      for (int j = 0; j < 2; ++j) {
        float4 v = make_float4(0.0f, 0.0f, 0.0f, 0.0f);
        if (sok) v = *reinterpret_cast<const float4*>(x2 + x2base + (kn * CK + chp0 + j) * HW);
        sreg[j] = v;
      }
    }
    __builtin_amdgcn_sched_barrier(0);

    // 3) compute, LDS reads double-buffered across the channel loop
    const float* lb = &x2s[(k & 1) * BUFF + ldro];
    float xr[2][16];
    ldx2(lb, xr[0]);
#pragma unroll
    for (int c = 0; c < CK; ++c) {
      if (c + 1 < CK) ldx2(lb + (c + 1) * CH_TILE, xr[(c + 1) & 1]);
      const float* av = a4[c];
      const float* xv = xr[c & 1];
#pragma unroll
      for (int dx = 0; dx < ND; ++dx)
#pragma unroll
        for (int i = 0; i < NPIX; ++i)
          acc[dx][i] = fmaf(av[i], xv[i + dx], acc[dx][i]);
    }

    // 4) commit next chunk into the other buffer
    if (kn < NCHUNK) {
#pragma unroll
      for (int j = 0; j < 2; ++j)
        *reinterpret_cast<float4*>(&x2s[(kn & 1) * BUFF + (chp0 + j) * CH_TILE + sldso]) = sreg[j];
    }
    __syncthreads();
  }

  // --- epilogue: mean + LeakyReLU + float4 stores (address set unchanged by remap)
  const int obase = (b * NDISP + wv * ND) * HW + (h0 + r) * Ww + w0 + cb;
#pragma unroll
  for (int dx = 0; dx < ND; ++dx) {
    float4 v0, v1;
    float t;
    t = acc[dx][0] * SCALE; v0.x = fmaxf(t, t * SLOPE);
    t = acc[dx][1] * SCALE; v0.y = fmaxf(t, t * SLOPE);
    t = acc[dx][2] * SCALE; v0.z = fmaxf(t, t * SLOPE);
    t = acc[dx][3] * SCALE; v0.w = fmaxf(t, t * SLOPE);
    t = acc[dx][4] * SCALE; v1.x = fmaxf(t, t * SLOPE);
    t = acc[dx][5] * SCALE; v1.y = fmaxf(t, t * SLOPE);
    t = acc[dx][6] * SCALE; v1.z = fmaxf(t, t * SLOPE);
    t = acc[dx][7] * SCALE; v1.w = fmaxf(t, t * SLOPE);
    float* po = out + obase + dx * HW;
    *reinterpret_cast<float4*>(po)     = v0;
    *reinterpret_cast<float4*>(po + 4) = v1;
  }
}

extern "C" void kernel_launch(void* const* d_in, const int* in_sizes, int n_in,
                              void* d_out, int out_size, void* d_ws, size_t ws_size,
                              hipStream_t stream) {
  const float* x1 = (const float*)d_in[0];
  const float* x2 = (const float*)d_in[1];
  float* out = (float*)d_out;
  dim3 grid(Ww / TW, Hh / TH, Bb);   // 4 x 16 x 8 = 512 blocks, 576 thr (9 waves)
  corr81_kernel<<<grid, NTHREADS, 0, stream>>>(x1, x2, out);
}

// Round 2
// 444.959 us; speedup vs baseline: 1.3438x; 1.3438x over previous
//
#include <hip/hip_runtime.h>

// FlowNet correlation, max_disp=4 -> 81 displacement channels, mean over C, LeakyReLU(0.1).
// B=8 C=128 H=128 W=256 fp32 NCHW.
//
// R4: LDS-free, barrier-free. Block = 576 threads = 9 independent waves; wave wv owns
// displacement row dy=wv over an 8x64 spatial tile, acc[9 dx][8 px] in regs.
//
// Rationale (R2 counters: VALUBusy 22.8%, occupancy = 1 block/CU, all pipes idle):
// R2 was a barrier convoy -- 32 chunk barriers x 9 waves with nothing co-resident to
// cover them. But the only inter-wave sharing is reuse-through-cache: all 9 waves read
// the SAME x1 tile (dy-independent -> L1 broadcast), and x2 rows offset by dy
// (16-row halo ~5KB/channel -> L1-resident). So read both operands straight from
// global with per-channel register ping-pong; no LDS, no __syncthreads at all.
// R3 lesson: allocator tops out ~84 VGPR here; no sched_barriers, modest live set
// (acc 72 + ping-pong 48), let the compiler schedule. Guard metric: WRITE_SIZE must
// stay ~83MB (output only). Scratch spill = regression.
//
// Boundary: gw = w0+cb-4 == 4 (mod 8), W = 256 -> each of the 4 float4 segments of a
// lane's 16-float x2 window is FULLY in or FULLY out of [0,W). 4 per-lane bools,
// no per-element masks. Row validity folded into the same predicates.

constexpr int MAXD = 4;
constexpr int ND   = 9;            // displacements per axis
constexpr int NDISP = 81;
constexpr int Bb = 8, Cc = 128, Hh = 128, Ww = 256;
constexpr int TH = 8, TW = 64, NPIX = 8;
constexpr int NTHREADS = ND * 64;  // 576
constexpr int HW = Hh * Ww;        // 32768
constexpr float SCALE = 1.0f / 128.0f;
constexpr float SLOPE = 0.1f;

__global__ __launch_bounds__(NTHREADS, 1)
void corr81_kernel(const float* __restrict__ x1, const float* __restrict__ x2,
                   float* __restrict__ out) {
  const int tid = threadIdx.x;
  const int wv  = tid >> 6;          // dy = wv, 0..8
  const int l   = tid & 63;
  const int r   = l >> 3;            // pixel row in tile, 0..7
  const int cb  = (l & 7) << 3;      // pixel col base, 0..56

  const int w0 = blockIdx.x * TW;
  const int h0 = blockIdx.y * TH;
  const int b  = blockIdx.z;

  // --- x1 address (row always in range; cols w0+cb..+7 always in range)
  const int x1base = (b * Cc * Hh + h0 + r) * Ww + w0 + cb;

  // --- x2 address + segment predicates
  const int gh2 = h0 + r + wv - MAXD;           // x2 row for this lane
  const bool rowok = (gh2 >= 0) && (gh2 < Hh);
  const int gw2 = w0 + cb - MAXD;               // leftmost col of 16-float window
  bool ok[4];
#pragma unroll
  for (int s = 0; s < 4; ++s) {
    const int c0 = gw2 + 4 * s;
    ok[s] = rowok && (c0 >= 0) && (c0 + 3 < Ww);
  }
  const int ghc = rowok ? gh2 : 0;              // clamped: base stays in-allocation
  const int x2base = b * (Cc * HW) + ghc * Ww + gw2;

  float acc[ND][NPIX];
#pragma unroll
  for (int dx = 0; dx < ND; ++dx)
#pragma unroll
    for (int i = 0; i < NPIX; ++i) acc[dx][i] = 0.0f;

  auto ldx1 = [&](int ch, float* dst) {
    const float* p = x1 + x1base + ch * HW;
    float4 t0 = *reinterpret_cast<const float4*>(p);
    float4 t1 = *reinterpret_cast<const float4*>(p + 4);
    dst[0] = t0.x; dst[1] = t0.y; dst[2] = t0.z; dst[3] = t0.w;
    dst[4] = t1.x; dst[5] = t1.y; dst[6] = t1.z; dst[7] = t1.w;
  };
  auto ldx2 = [&](int ch, float* dst) {
    const float* p = x2 + x2base + ch * HW;
#pragma unroll
    for (int s = 0; s < 4; ++s) {
      float4 q = make_float4(0.0f, 0.0f, 0.0f, 0.0f);
      if (ok[s]) q = *reinterpret_cast<const float4*>(p + 4 * s);
      dst[4 * s + 0] = q.x; dst[4 * s + 1] = q.y;
      dst[4 * s + 2] = q.z; dst[4 * s + 3] = q.w;
    }
  };

  float a0[NPIX], a1[NPIX], xa[16], xb[16];

#define FMA_BLOCK(av, xv)                                   \
  _Pragma("unroll")                                         \
  for (int dx = 0; dx < ND; ++dx)                           \
    _Pragma("unroll")                                       \
    for (int i = 0; i < NPIX; ++i)                          \
      acc[dx][i] = fmaf((av)[i], (xv)[i + dx], acc[dx][i]);

  // prologue: channel 0 into set A
  ldx1(0, a0);
  ldx2(0, xa);

#pragma unroll 1
  for (int ch = 0; ch < Cc; ch += 2) {
    // prefetch ch+1 into set B (always valid: Cc even)
    ldx1(ch + 1, a1);
    ldx2(ch + 1, xb);
    FMA_BLOCK(a0, xa)
    // prefetch ch+2 into set A
    if (ch + 2 < Cc) {
      ldx1(ch + 2, a0);
      ldx2(ch + 2, xa);
    }
    FMA_BLOCK(a1, xb)
  }
#undef FMA_BLOCK

  // --- epilogue: mean + LeakyReLU + coalesced float4 stores
  const int obase = (b * NDISP + wv * ND) * HW + (h0 + r) * Ww + w0 + cb;
#pragma unroll
  for (int dx = 0; dx < ND; ++dx) {
    float4 v0, v1;
    float t;
    t = acc[dx][0] * SCALE; v0.x = fmaxf(t, t * SLOPE);
    t = acc[dx][1] * SCALE; v0.y = fmaxf(t, t * SLOPE);
    t = acc[dx][2] * SCALE; v0.z = fmaxf(t, t * SLOPE);
    t = acc[dx][3] * SCALE; v0.w = fmaxf(t, t * SLOPE);
    t = acc[dx][4] * SCALE; v1.x = fmaxf(t, t * SLOPE);
    t = acc[dx][5] * SCALE; v1.y = fmaxf(t, t * SLOPE);
    t = acc[dx][6] * SCALE; v1.z = fmaxf(t, t * SLOPE);
    t = acc[dx][7] * SCALE; v1.w = fmaxf(t, t * SLOPE);
    float* po = out + obase + dx * HW;
    *reinterpret_cast<float4*>(po)     = v0;
    *reinterpret_cast<float4*>(po + 4) = v1;
  }
}

extern "C" void kernel_launch(void* const* d_in, const int* in_sizes, int n_in,
                              void* d_out, int out_size, void* d_ws, size_t ws_size,
                              hipStream_t stream) {
  const float* x1 = (const float*)d_in[0];
  const float* x2 = (const float*)d_in[1];
  float* out = (float*)d_out;
  dim3 grid(Ww / TW, Hh / TH, Bb);   // 4 x 16 x 8 = 512 blocks, 576 thr (9 waves)
  corr81_kernel<<<grid, NTHREADS, 0, stream>>>(x1, x2, out);
}

// Round 3
// 419.357 us; speedup vs baseline: 1.4258x; 1.0611x over previous
//
#include <hip/hip_runtime.h>

// FlowNet correlation, max_disp=4 -> 81 channels, mean over C=128, LeakyReLU(0.1).
// B=8 C=128 H=128 W=256 fp32 NCHW.
//
// R5: MLP (in-flight bytes) is the bottleneck. R2=232us @1.63TB/s and R4=262us @~2TB/s
// are both explained by Little's law: ~5-8KB in flight per CU at ~900cy HBM latency.
// Fix: global_load_lds staging (zero VGPR per outstanding load), 4 LDS buffers,
// prefetch distance 3 chunks, counted vmcnt (never 0 in steady state) + raw s_barrier
// so the queue never drains. x1 AND x2 staged (x1 read from LDS -> no 9x redundancy).
// In-flight ~27-40KB/CU -> HBM-BW-bound; predict 90-140us.
//
// Staging layout (m104: gll dest = wave-uniform base + lane*16, strictly linear):
// chunk = CK=2 channels = [x2: 2x(16x72)=2304 floats][x1: 2x(8x64)=1024] = 3328 floats
// = 13 groups of 256 floats. Waves 0-3 stage 2 groups, waves 4-8 stage 1 group.
// OOB x2 lanes load a CLAMPED address; after the counted vmcnt drain, each wave
// zero-writes its own invalid slots (chunk-invariant) before the barrier.

constexpr int MAXD = 4;
constexpr int ND   = 9;
constexpr int NDISP = 81;
constexpr int Bb = 8, Cc = 128, Hh = 128, Ww = 256;
constexpr int TH = 8, TW = 64, NPIX = 8;
constexpr int CK = 2;                  // channels per chunk
constexpr int NCHUNK = Cc / CK;        // 64
constexpr int X2ROWS = TH + 2 * MAXD;  // 16
constexpr int X2COLS = 72;             // 4 + 64 + 4 (unpadded: gll is linear)
constexpr int X2T = X2ROWS * X2COLS;   // 1152 floats / channel
constexpr int X1T = TH * TW;           // 512 floats / channel
constexpr int X2R = CK * X2T;          // 2304 floats (groups 0..8)
constexpr int CHF = CK * (X2T + X1T);  // 3328 floats / buffer
constexpr int NBUF = 4;
constexpr int NTHREADS = ND * 64;      // 576
constexpr int HW = Hh * Ww;            // 32768
constexpr int CHSTRIDE = CK * HW;      // float stride between chunks
constexpr float SCALE = 1.0f / 128.0f;
constexpr float SLOPE = 0.1f;

__global__ __launch_bounds__(NTHREADS, 1)
void corr81_kernel(const float* __restrict__ x1, const float* __restrict__ x2,
                   float* __restrict__ out) {
  const int tid = threadIdx.x;
  const int wv  = tid >> 6;            // dy row, 0..8
  const int l   = tid & 63;
  const int r   = l >> 3;              // pixel row in tile
  const int cb  = (l & 7) << 3;        // pixel col base

  const int w0 = blockIdx.x * TW;
  const int h0 = blockIdx.y * TH;
  const int b  = blockIdx.z;

  __shared__ __align__(16) float lds[NBUF * CHF];   // 53,248 B

  // ---- staging precompute (chunk-invariant) ----
  const int jn = (wv < 4) ? 2 : 1;     // groups this wave stages per chunk
  const float* src[2];
  int  grp[2], zofs[2];
  bool val[2];
#pragma unroll
  for (int j = 0; j < 2; ++j) {
    const int g = (wv < 4) ? (2 * wv + j) : (8 + (wv - 4));
    grp[j] = g;
    const int f = 256 * g + 4 * l;     // flat float index of this lane's 16B slot
    bool v = true;
    const float* p;
    if (f < X2R) {                     // x2 region
      const int ch  = f / X2T;
      const int rem = f - ch * X2T;
      const int row = rem / X2COLS;
      const int col = rem - row * X2COLS;
      const int gr = h0 - MAXD + row;
      const int gc = w0 - MAXD + col;
      v = (gr >= 0) && (gr < Hh) && (gc >= 0) && (gc <= Ww - 4);
      const int grc = gr < 0 ? 0 : (gr > Hh - 1 ? Hh - 1 : gr);
      const int gcc = gc < 0 ? 0 : (gc > Ww - 4 ? Ww - 4 : gc);
      p = x2 + ((b * Cc + ch) * HW + grc * Ww + gcc);
    } else {                           // x1 region (always in-bounds)
      const int f2  = f - X2R;
      const int ch  = f2 / X1T;
      const int rem = f2 - ch * X1T;
      const int row = rem >> 6;
      const int col = rem & 63;
      p = x1 + ((b * Cc + ch) * HW + (h0 + row) * Ww + (w0 + col));
    }
    src[j] = p; val[j] = v; zofs[j] = 256 * g + 4 * l;
  }

  auto stage = [&](int kc) {
    const int bb = (kc & (NBUF - 1)) * CHF;
#pragma unroll
    for (int j = 0; j < 2; ++j)
      if (j < jn)
        __builtin_amdgcn_global_load_lds(
            (const __attribute__((address_space(1))) void*)(src[j] + kc * CHSTRIDE),
            (__attribute__((address_space(3))) void*)(&lds[bb + 256 * grp[j]]),
            16, 0, 0);
  };
  auto fixz = [&](int kc) {            // zero this wave's OOB slots (after its vmcnt drain)
    const int bb = (kc & (NBUF - 1)) * CHF;
#pragma unroll
    for (int j = 0; j < 2; ++j)
      if (j < jn && !val[j])
        *reinterpret_cast<float4*>(&lds[bb + zofs[j]]) = make_float4(0.f, 0.f, 0.f, 0.f);
  };
  // counted waits: drain everything except `keep` chunks' worth of this wave's stages
  auto wait2 = [&]() { if (wv < 4) asm volatile("s_waitcnt vmcnt(4)" ::: "memory");
                       else        asm volatile("s_waitcnt vmcnt(2)" ::: "memory"); };
  auto wait1 = [&]() { if (wv < 4) asm volatile("s_waitcnt vmcnt(2)" ::: "memory");
                       else        asm volatile("s_waitcnt vmcnt(1)" ::: "memory"); };
  auto wait0 = [&]() { asm volatile("s_waitcnt vmcnt(0)" ::: "memory"); };
  auto bar = [&]() {
    asm volatile("s_waitcnt lgkmcnt(0)" ::: "memory");
    __builtin_amdgcn_s_barrier();
    asm volatile("" ::: "memory");
  };

  // ---- prologue: stage chunks 0..2, drain chunk 0, zero buf0 OOB slots ----
  stage(0); stage(1); stage(2);
  wait2();
  fixz(0);
  bar();

  float acc[ND][NPIX];
#pragma unroll
  for (int dx = 0; dx < ND; ++dx)
#pragma unroll
    for (int i = 0; i < NPIX; ++i) acc[dx][i] = 0.0f;

#pragma unroll 1
  for (int k = 0; k < NCHUNK; ++k) {
    if (k + 3 < NCHUNK) stage(k + 3);  // into buf (k+3)&3 == (k-1)&3, freed last barrier

    const int bb = (k & (NBUF - 1)) * CHF;
#pragma unroll
    for (int c = 0; c < CK; ++c) {
      const float* xp = &lds[bb + c * X2T + (r + wv) * X2COLS + cb];
      float4 q0 = *reinterpret_cast<const float4*>(xp);
      float4 q1 = *reinterpret_cast<const float4*>(xp + 4);
      float4 q2 = *reinterpret_cast<const float4*>(xp + 8);
      float4 q3 = *reinterpret_cast<const float4*>(xp + 12);
      const float* ap = &lds[bb + X2R + c * X1T + r * TW + cb];
      float4 t0 = *reinterpret_cast<const float4*>(ap);
      float4 t1 = *reinterpret_cast<const float4*>(ap + 4);
      const float xr[16] = {q0.x, q0.y, q0.z, q0.w, q1.x, q1.y, q1.z, q1.w,
                            q2.x, q2.y, q2.z, q2.w, q3.x, q3.y, q3.z, q3.w};
      const float av[8]  = {t0.x, t0.y, t0.z, t0.w, t1.x, t1.y, t1.z, t1.w};
#pragma unroll
      for (int dx = 0; dx < ND; ++dx)
#pragma unroll
        for (int i = 0; i < NPIX; ++i)
          acc[dx][i] = fmaf(av[i], xr[i + dx], acc[dx][i]);
    }

    if (k + 1 < NCHUNK) {
      // drain this wave's chunk-(k+1) stages; keep the younger ones in flight
      if      (k + 3 < NCHUNK) wait2();   // {k+2,k+3} remain
      else if (k + 2 < NCHUNK) wait1();   // {k+2} remains
      else                     wait0();   // nothing younger
      fixz(k + 1);
      bar();
    }
  }

  // ---- epilogue: mean + LeakyReLU + coalesced float4 stores ----
  const int obase = (b * NDISP + wv * ND) * HW + (h0 + r) * Ww + w0 + cb;
#pragma unroll
  for (int dx = 0; dx < ND; ++dx) {
    float4 v0, v1;
    float t;
    t = acc[dx][0] * SCALE; v0.x = fmaxf(t, t * SLOPE);
    t = acc[dx][1] * SCALE; v0.y = fmaxf(t, t * SLOPE);
    t = acc[dx][2] * SCALE; v0.z = fmaxf(t, t * SLOPE);
    t = acc[dx][3] * SCALE; v0.w = fmaxf(t, t * SLOPE);
    t = acc[dx][4] * SCALE; v1.x = fmaxf(t, t * SLOPE);
    t = acc[dx][5] * SCALE; v1.y = fmaxf(t, t * SLOPE);
    t = acc[dx][6] * SCALE; v1.z = fmaxf(t, t * SLOPE);
    t = acc[dx][7] * SCALE; v1.w = fmaxf(t, t * SLOPE);
    float* po = out + obase + dx * HW;
    *reinterpret_cast<float4*>(po)     = v0;
    *reinterpret_cast<float4*>(po + 4) = v1;
  }
}

extern "C" void kernel_launch(void* const* d_in, const int* in_sizes, int n_in,
                              void* d_out, int out_size, void* d_ws, size_t ws_size,
                              hipStream_t stream) {
  const float* x1 = (const float*)d_in[0];
  const float* x2 = (const float*)d_in[1];
  float* out = (float*)d_out;
  dim3 grid(Ww / TW, Hh / TH, Bb);   // 4 x 16 x 8 = 512 blocks, 576 thr (9 waves)
  corr81_kernel<<<grid, NTHREADS, 0, stream>>>(x1, x2, out);
}